// Round 22
// baseline (454.711 us; speedup 1.0000x reference)
//
#include <hip/hip_runtime.h>
#include <hip/hip_bf16.h>

#define DEV static __device__ __forceinline__

typedef __attribute__((ext_vector_type(8))) _Float16 half8;   // A/B frag: 8 fp16 = 4 VGPR
typedef __attribute__((ext_vector_type(4))) float f32x4;      // C/D frag

constexpr int Bc = 4, Tc = 2048, Dc = 2048, Hc = 16;          // HD = 128

DEV ushort f2h(float f) { _Float16 h = (_Float16)f; return __builtin_bit_cast(ushort, h); }
DEV float  h2f(ushort u) { return (float)__builtin_bit_cast(_Float16, u); }
DEV uint pk2h(float a, float b) {
  return __builtin_bit_cast(uint, __builtin_amdgcn_cvt_pkrtz(a, b));
}

DEV f32x4 MFMA(half8 a, half8 b, f32x4 c) {
  return __builtin_amdgcn_mfma_f32_16x16x32_f16(a, b, c, 0, 0, 0);
}

DEV void async_cp16(void* lds, const void* g) {
  __builtin_amdgcn_global_load_lds((const __attribute__((address_space(1))) void*)g,
                                   (__attribute__((address_space(3))) void*)lds,
                                   16, 0, 0);
}

// ---- fused convert: x (blk<16384) + 4 weights (blk>=16384, Wq/Wk RoPE-perm)
// GRID = 32768.
__global__ __launch_bounds__(256) void cvtall(const float* __restrict__ x,
                                              const float* __restrict__ w0,
                                              const float* __restrict__ w1,
                                              const float* __restrict__ w2,
                                              const float* __restrict__ w3,
                                              ushort* __restrict__ xb,
                                              ushort* __restrict__ wb) {
  const int blk = (int)blockIdx.x;
  if (blk < 16384) {                    // x: 4M vec4
    const int i = blk * 256 + (int)threadIdx.x;
    const float4 v = ((const float4*)x)[i];
    ushort4 o;
    o.x = f2h(v.x); o.y = f2h(v.y); o.z = f2h(v.z); o.w = f2h(v.w);
    ((ushort4*)xb)[i] = o;
    return;
  }
  const int wblk = blk - 16384;         // 0..16383 (4096 blocks per weight)
  const int wsel = wblk >> 12;          // 0:Wq 1:Wk 2:Wv 3:Wo
  const int i = (wblk & 4095) * 256 + (int)threadIdx.x;  // vec4 idx, 1M per W
  const float* in = (wsel == 0) ? w0 : (wsel == 1) ? w1 : (wsel == 2) ? w2 : w3;
  const float4 v = ((const float4*)in)[i];
  ushort4 o;
  o.x = f2h(v.x); o.y = f2h(v.y); o.z = f2h(v.z); o.w = f2h(v.w);
  int row = i >> 9;
  const int cidx = i & 511;
  if (wsel < 2) {                       // RoPE row permutation for Wq/Wk
    const int h = row >> 7, fr = row & 127;
    const int s_ = fr >> 6, j = fr & 63;
    row = h * 128 + (j >> 4) * 32 + s_ * 16 + (j & 15);
  }
  ((ushort4*)wb)[((size_t)wsel << 20) + row * 512 + cidx] = o;
}

// ---------------- fused QKV GEMM 256x256, BK=64, 2-slot dbuf --------------
// r22: 1 barrier + 1 vmcnt(0) per 64-K (half of r17's per-32K), following the
// measured gradient "coarser wins" (72/64/63us ladder). Stage t+1 issued at
// iter start into the opposite slot; drain at iter end covered by 24 ds_read
// + 64 MFMA. Read swizzle: granule (ks*4+g)^(row&7) spreads 8 rows over the
// 128B row (conflict-free; 16-row alias = free 2-way); source pre-swizzled.
__global__ __launch_bounds__(512, 2) void gemmqkv(const ushort* __restrict__ A,
                                                  const ushort* __restrict__ Bw,
                                                  ushort* __restrict__ Cq,
                                                  const float* __restrict__ cs,
                                                  const float* __restrict__ sn) {
  __shared__ ushort As[2][256 * 64];
  __shared__ ushort Bs[2][256 * 64];
  const int tid = threadIdx.x;                 // 0..511
  const int lane = tid & 63, wid = tid >> 6;   // 8 waves
  const int g = lane >> 4, q16 = lane & 15;
  const int wm = wid >> 2, wn = wid & 3;       // 2M x 4N

  const int flat = (int)blockIdx.x;            // 0..767
  const int xcd = flat & 7, idx = flat >> 3;   // idx 0..95
  const int bm = xcd * 4 + (idx & 3);
  const int bn = idx >> 2;                     // 0..23
  const ushort* Ab = A + (size_t)bm * 256 * Dc;
  const ushort* Bb = Bw + (size_t)bn * 256 * Dc;

  // tile = 256 rows x 64 cols (8 granules/row). 4 cp16/thread per matrix.
#define STAGE64(KT, BUF) do {                                                  \
    _Pragma("unroll") for (int p_ = 0; p_ < 4; ++p_) {                         \
      const int c_ = p_ * 512 + tid;                                           \
      const int row_ = c_ >> 3, gl_ = c_ & 7;                                  \
      const int col_ = (KT) * 64 + ((gl_ ^ (row_ & 7)) << 3);                  \
      async_cp16(&As[BUF][(p_ * 512 + wid * 64) * 8],                          \
                 Ab + (size_t)row_ * Dc + col_);                               \
    }                                                                          \
    _Pragma("unroll") for (int p_ = 0; p_ < 4; ++p_) {                         \
      const int c_ = p_ * 512 + tid;                                           \
      const int row_ = c_ >> 3, gl_ = c_ & 7;                                  \
      const int col_ = (KT) * 64 + ((gl_ ^ (row_ & 7)) << 3);                  \
      async_cp16(&Bs[BUF][(p_ * 512 + wid * 64) * 8],                          \
                 Bb + (size_t)row_ * Dc + col_);                               \
    }                                                                          \
  } while (0)

  // frag read: row r, k-half KS: ushort addr = r*64 + (((KS)*4+g)^(r&7))*8
#define READS64(BUF, KS) do {                                                  \
    const ushort* Asb_ = As[BUF];                                              \
    const ushort* Bsb_ = Bs[BUF];                                              \
    _Pragma("unroll") for (int nf_ = 0; nf_ < 4; ++nf_) {                      \
      const int r_ = wn * 64 + nf_ * 16 + q16;                                 \
      bf[nf_] = *(const half8*)&Bsb_[r_ * 64 + ((((KS) * 4 + g) ^ (r_ & 7)) << 3)]; \
    }                                                                          \
    _Pragma("unroll") for (int mf_ = 0; mf_ < 4; ++mf_) {                      \
      const int r_ = wm * 128 + mf_ * 16 + q16;                                \
      af0[mf_] = *(const half8*)&Asb_[r_ * 64 + ((((KS) * 4 + g) ^ (r_ & 7)) << 3)]; \
    }                                                                          \
    _Pragma("unroll") for (int mf_ = 0; mf_ < 4; ++mf_) {                      \
      const int r_ = wm * 128 + 64 + mf_ * 16 + q16;                           \
      af1[mf_] = *(const half8*)&Asb_[r_ * 64 + ((((KS) * 4 + g) ^ (r_ & 7)) << 3)]; \
    }                                                                          \
  } while (0)

  f32x4 acc[8][4] = {};

  STAGE64(0, 0);
  asm volatile("s_waitcnt vmcnt(0)" ::: "memory");
  __builtin_amdgcn_s_barrier();
  __builtin_amdgcn_sched_barrier(0);

#pragma unroll 1
  for (int t = 0; t < 32; ++t) {
    const int rb = t & 1;
    if (t + 1 < 32) STAGE64(t + 1, rb ^ 1);   // opposite slot: safe

    half8 af0[4], af1[4], bf[4];
    READS64(rb, 0);
    __builtin_amdgcn_s_setprio(1);
#pragma unroll
    for (int mf = 0; mf < 4; ++mf)
#pragma unroll
      for (int nf = 0; nf < 4; ++nf)
        acc[mf][nf] = MFMA(af0[mf], bf[nf], acc[mf][nf]);
#pragma unroll
    for (int mf = 0; mf < 4; ++mf)
#pragma unroll
      for (int nf = 0; nf < 4; ++nf)
        acc[4 + mf][nf] = MFMA(af1[mf], bf[nf], acc[4 + mf][nf]);
    __builtin_amdgcn_s_setprio(0);

    READS64(rb, 1);
    __builtin_amdgcn_s_setprio(1);
#pragma unroll
    for (int mf = 0; mf < 4; ++mf)
#pragma unroll
      for (int nf = 0; nf < 4; ++nf)
        acc[mf][nf] = MFMA(af0[mf], bf[nf], acc[mf][nf]);
#pragma unroll
    for (int mf = 0; mf < 4; ++mf)
#pragma unroll
      for (int nf = 0; nf < 4; ++nf)
        acc[4 + mf][nf] = MFMA(af1[mf], bf[nf], acc[4 + mf][nf]);
    __builtin_amdgcn_s_setprio(0);

    asm volatile("s_waitcnt vmcnt(0)" ::: "memory");  // t+1 landed (covered)
    __builtin_amdgcn_s_barrier();                     // slot rb readers done
    __builtin_amdgcn_sched_barrier(0);
  }
#undef READS64
#undef STAGE64

  ushort* C = Cq + (size_t)(bn >> 3) * ((size_t)8192 * Dc);
  const int bn8 = bn & 7;
  const int m00 = bm * 256 + wm * 128 + g * 4;
  const int n0 = bn8 * 256 + wn * 64 + q16;

  if (bn < 16) {
#pragma unroll
    for (int mf = 0; mf < 8; ++mf)
#pragma unroll
      for (int p = 0; p < 2; ++p) {
        const int j = ((wn & 1) * 2 + p) * 16 + q16;
#pragma unroll
        for (int r = 0; r < 4; ++r) {
          const int m = m00 + mf * 16 + r;
          const int t = m & (Tc - 1);
          const float c = cs[t * 128 + j];
          const float s_ = sn[t * 128 + j];
          const float lo = acc[mf][2 * p][r];
          const float hi = acc[mf][2 * p + 1][r];
          C[(size_t)m * Dc + n0 + (2 * p) * 16] = f2h(lo * c - hi * s_);
          C[(size_t)m * Dc + n0 + (2 * p + 1) * 16] = f2h(hi * c + lo * s_);
        }
      }
  } else {
#pragma unroll
    for (int mf = 0; mf < 8; ++mf)
#pragma unroll
      for (int nf = 0; nf < 4; ++nf) {
        const int m0 = m00 + mf * 16;
        const int n = n0 + nf * 16;
#pragma unroll
        for (int r = 0; r < 4; ++r)
          C[(size_t)(m0 + r) * Dc + n] = f2h(acc[mf][nf][r]);
      }
  }
}

// ---------------- GEMM 256x256 BK=64 dbuf (final projection, f32 out) ------
template <typename OutT>
__global__ __launch_bounds__(512, 2) void gemm256(const ushort* __restrict__ A,
                                                  const ushort* __restrict__ Bw,
                                                  OutT* __restrict__ C) {
  __shared__ ushort As[2][256 * 64];
  __shared__ ushort Bs[2][256 * 64];
  const int tid = threadIdx.x;
  const int lane = tid & 63, wid = tid >> 6;
  const int g = lane >> 4, q16 = lane & 15;
  const int wm = wid >> 2, wn = wid & 3;

  const int flat = (int)blockIdx.x;            // 0..255
  const int xcd = flat & 7, idx = flat >> 3;
  const int bm = xcd * 4 + (idx & 3);
  const int bn = idx >> 2;
  const ushort* Ab = A + (size_t)bm * 256 * Dc;
  const ushort* Bb = Bw + (size_t)bn * 256 * Dc;

#define STAGE64(KT, BUF) do {                                                  \
    _Pragma("unroll") for (int p_ = 0; p_ < 4; ++p_) {                         \
      const int c_ = p_ * 512 + tid;                                           \
      const int row_ = c_ >> 3, gl_ = c_ & 7;                                  \
      const int col_ = (KT) * 64 + ((gl_ ^ (row_ & 7)) << 3);                  \
      async_cp16(&As[BUF][(p_ * 512 + wid * 64) * 8],                          \
                 Ab + (size_t)row_ * Dc + col_);                               \
    }                                                                          \
    _Pragma("unroll") for (int p_ = 0; p_ < 4; ++p_) {                         \
      const int c_ = p_ * 512 + tid;                                           \
      const int row_ = c_ >> 3, gl_ = c_ & 7;                                  \
      const int col_ = (KT) * 64 + ((gl_ ^ (row_ & 7)) << 3);                  \
      async_cp16(&Bs[BUF][(p_ * 512 + wid * 64) * 8],                          \
                 Bb + (size_t)row_ * Dc + col_);                               \
    }                                                                          \
  } while (0)

#define READS64(BUF, KS) do {                                                  \
    const ushort* Asb_ = As[BUF];                                              \
    const ushort* Bsb_ = Bs[BUF];                                              \
    _Pragma("unroll") for (int nf_ = 0; nf_ < 4; ++nf_) {                      \
      const int r_ = wn * 64 + nf_ * 16 + q16;                                 \
      bf[nf_] = *(const half8*)&Bsb_[r_ * 64 + ((((KS) * 4 + g) ^ (r_ & 7)) << 3)]; \
    }                                                                          \
    _Pragma("unroll") for (int mf_ = 0; mf_ < 4; ++mf_) {                      \
      const int r_ = wm * 128 + mf_ * 16 + q16;                                \
      af0[mf_] = *(const half8*)&Asb_[r_ * 64 + ((((KS) * 4 + g) ^ (r_ & 7)) << 3)]; \
    }                                                                          \
    _Pragma("unroll") for (int mf_ = 0; mf_ < 4; ++mf_) {                      \
      const int r_ = wm * 128 + 64 + mf_ * 16 + q16;                           \
      af1[mf_] = *(const half8*)&Asb_[r_ * 64 + ((((KS) * 4 + g) ^ (r_ & 7)) << 3)]; \
    }                                                                          \
  } while (0)

  f32x4 acc[8][4] = {};

  STAGE64(0, 0);
  asm volatile("s_waitcnt vmcnt(0)" ::: "memory");
  __builtin_amdgcn_s_barrier();
  __builtin_amdgcn_sched_barrier(0);

#pragma unroll 1
  for (int t = 0; t < 32; ++t) {
    const int rb = t & 1;
    if (t + 1 < 32) STAGE64(t + 1, rb ^ 1);

    half8 af0[4], af1[4], bf[4];
    READS64(rb, 0);
    __builtin_amdgcn_s_setprio(1);
#pragma unroll
    for (int mf = 0; mf < 4; ++mf)
#pragma unroll
      for (int nf = 0; nf < 4; ++nf)
        acc[mf][nf] = MFMA(af0[mf], bf[nf], acc[mf][nf]);
#pragma unroll
    for (int mf = 0; mf < 4; ++mf)
#pragma unroll
      for (int nf = 0; nf < 4; ++nf)
        acc[4 + mf][nf] = MFMA(af1[mf], bf[nf], acc[4 + mf][nf]);
    __builtin_amdgcn_s_setprio(0);

    READS64(rb, 1);
    __builtin_amdgcn_s_setprio(1);
#pragma unroll
    for (int mf = 0; mf < 4; ++mf)
#pragma unroll
      for (int nf = 0; nf < 4; ++nf)
        acc[mf][nf] = MFMA(af0[mf], bf[nf], acc[mf][nf]);
#pragma unroll
    for (int mf = 0; mf < 4; ++mf)
#pragma unroll
      for (int nf = 0; nf < 4; ++nf)
        acc[4 + mf][nf] = MFMA(af1[mf], bf[nf], acc[4 + mf][nf]);
    __builtin_amdgcn_s_setprio(0);

    asm volatile("s_waitcnt vmcnt(0)" ::: "memory");
    __builtin_amdgcn_s_barrier();
    __builtin_amdgcn_sched_barrier(0);
  }
#undef READS64
#undef STAGE64

  const int m00 = bm * 256 + wm * 128 + g * 4;
  const int n0 = bn * 256 + wn * 64 + q16;
#pragma unroll
  for (int mf = 0; mf < 8; ++mf)
#pragma unroll
    for (int nf = 0; nf < 4; ++nf) {
      const int m0 = m00 + mf * 16;
      const int n = n0 + nf * 16;
#pragma unroll
      for (int r = 0; r < 4; ++r) {
        const float v = acc[mf][nf][r];
        if constexpr (sizeof(OutT) == 2)
          C[(size_t)(m0 + r) * Dc + n] = (OutT)f2h(v);
        else
          C[(size_t)(m0 + r) * Dc + n] = (OutT)v;
      }
    }
}

// ---------------- causal flash attention (2 q-chains / wave) ----------------
// EXACT round-12/13 version (best-known 162us). Q/K feature-PERMUTED.
__global__ __launch_bounds__(512, 2) void attn(const ushort* __restrict__ Q,
                                               const ushort* __restrict__ K,
                                               const ushort* __restrict__ V,
                                               ushort* __restrict__ O) {
  __shared__ ushort Ks[2][64 * 128];   // [kv][d], XOR-swizzled (granule ^= kv&7)
  __shared__ ushort Vt[2][128 * 64];   // [d][kv], XOR-swizzled rows

  const int tid = threadIdx.x;         // 0..511
  const int lane = tid & 63, wid = tid >> 6;   // wid 0..7
  const int g = lane >> 4, q16 = lane & 15;

  const int flat = (int)(blockIdx.x + 4 * blockIdx.y);    // 0..255
  const int xcd = flat & 7, idx = flat >> 3;              // idx 0..31
  const int bh = xcd + 8 * (idx & 7);                     // head-slot 0..63
  const int pr = idx >> 3;                                // supertile pair 0..3

  const int b = bh >> 4, h = bh & 15;
  const size_t headbase = ((size_t)b * Tc * Hc + h) * 128;  // t-stride = 2048
  const float SCL2 = 0.12751743f;      // log2(e)/sqrt(128)

  const int vdc = (wid & 3) * 4 + (lane & 3);         // 0..15: d = vdc*8..+7
  const int vkvp = (wid >> 2) * 16 + (lane >> 2);     // 0..31: kv pair

  uint4 vreg[2];

#define ISSUEK(KT, BUF) do {                                                   \
    const ushort* Kb_ = K + headbase + (size_t)(KT) * 64 * Dc;                 \
    _Pragma("unroll") for (int i_ = 0; i_ < 2; ++i_) {                         \
      const int c_ = i_ * 512 + tid;                                           \
      const int kv_ = c_ >> 4, gl_ = c_ & 15;                                  \
      async_cp16(&Ks[BUF][(i_ * 512 + wid * 64) * 8],                          \
                 Kb_ + (size_t)kv_ * Dc + ((gl_ ^ (kv_ & 7)) << 3));           \
    }                                                                          \
  } while (0)

#define LOADV(KT) do {                                                         \
    const ushort* p0_ = V + headbase + (size_t)((KT) * 64 + 2 * vkvp) * Dc +   \
                        vdc * 8;                                               \
    vreg[0] = *(const uint4*)p0_;                                              \
    vreg[1] = *(const uint4*)(p0_ + Dc);                                       \
  } while (0)

#define WRITEV(BUF) do {                                                       \
    const ushort* e0_ = (const ushort*)&vreg[0];                               \
    const ushort* e1_ = (const ushort*)&vreg[1];                               \
    _Pragma("unroll") for (int j_ = 0; j_ < 8; ++j_) {                         \
      const int d_ = vdc * 8 + j_;                                             \
      const unsigned w_ = (unsigned)e0_[j_] | ((unsigned)e1_[j_] << 16);       \
      *(unsigned*)&Vt[BUF][(d_ * 64 + 2 * vkvp) ^ ((d_ & 7) << 3)] = w_;       \
    }                                                                          \
  } while (0)

#pragma unroll 1
  for (int half = 0; half < 2; ++half) {
    const int q0 = (half ? pr : 7 - pr) * 256;
    const int qrow = q0 + wid * 32;          // wave owns rows qrow..qrow+31
    const int nt = q0 / 64 + 4;

    half8 qreg[2][4];
#pragma unroll
    for (int qf = 0; qf < 2; ++qf)
#pragma unroll
      for (int ds = 0; ds < 4; ++ds)
        qreg[qf][ds] = *(const half8*)(Q + headbase +
                       (size_t)(qrow + qf * 16 + q16) * Dc + ds * 32 + g * 8);

    f32x4 oacc[2][8] = {};             // O^T frags: row=d (g*4+r), col=q
    float m_[2] = {-1e30f, -1e30f};
    float l_[2] = {0.f, 0.f};          // per-lane partials

    __builtin_amdgcn_s_barrier();      // prior half done reading all LDS bufs
    __builtin_amdgcn_sched_barrier(0);
    ISSUEK(0, 0);
    LOADV(0);
    WRITEV(0);                         // compiler waits vmcnt for vreg here

#pragma unroll 1
    for (int kt = 0; kt < nt; ++kt) {
      const int cur = kt & 1;
      const int kv0 = kt * 64;
      asm volatile("s_waitcnt vmcnt(0) lgkmcnt(0)" ::: "memory");
      __builtin_amdgcn_s_barrier();
      __builtin_amdgcn_sched_barrier(0);
      if (kt + 1 < nt) {
        ISSUEK(kt + 1, cur ^ 1);
        LOADV(kt + 1);
      }

      if (kv0 <= qrow + 31) {          // wave-uniform
        const ushort* Ksb = Ks[cur];
        const ushort* Vtb = Vt[cur];
        f32x4 s[2][4] = {};
        __builtin_amdgcn_s_setprio(1);
#pragma unroll
        for (int ds = 0; ds < 4; ++ds) {
          half8 kf[4];
#pragma unroll
          for (int kvf = 0; kvf < 4; ++kvf) {
            const int kv = kvf * 16 + q16;
            kf[kvf] = *(const half8*)&Ksb[(kv * 128 + ds * 32 + g * 8) ^ ((kv & 7) << 3)];
          }
#pragma unroll
          for (int kvf = 0; kvf < 4; ++kvf)
#pragma unroll
            for (int qf = 0; qf < 2; ++qf)
              s[qf][kvf] = MFMA(kf[kvf], qreg[qf][ds], s[qf][kvf]);
        }
        __builtin_amdgcn_s_setprio(0);
        float pmax[2] = {-1e30f, -1e30f};
        if (kv0 + 63 > qrow) {
#pragma unroll
          for (int qf = 0; qf < 2; ++qf) {
            const int qg = qrow + qf * 16 + q16;
#pragma unroll
            for (int kvf = 0; kvf < 4; ++kvf)
#pragma unroll
              for (int r = 0; r < 4; ++r) {
                float v = s[qf][kvf][r];
                if ((kv0 + kvf * 16 + g * 4 + r) > qg) v = -1e30f;
                s[qf][kvf][r] = v;
                pmax[qf] = fmaxf(pmax[qf], v);
              }
          }
        } else {
#pragma unroll
          for (int qf = 0; qf < 2; ++qf)
#pragma unroll
            for (int kvf = 0; kvf < 4; ++kvf)
#pragma unroll
              for (int r = 0; r < 4; ++r)
                pmax[qf] = fmaxf(pmax[qf], s[qf][kvf][r]);
        }
#pragma unroll
        for (int qf = 0; qf < 2; ++qf) {
          pmax[qf] = fmaxf(pmax[qf], __shfl_xor(pmax[qf], 16));
          pmax[qf] = fmaxf(pmax[qf], __shfl_xor(pmax[qf], 32));
        }
        if (!__all((pmax[0] <= m_[0] + 16.f) & (pmax[1] <= m_[1] + 16.f))) {
#pragma unroll
          for (int qf = 0; qf < 2; ++qf) {
            const float mn2 = fmaxf(m_[qf], pmax[qf]);
            const float alpha = __builtin_exp2f((m_[qf] - mn2) * SCL2);
            m_[qf] = mn2;
            l_[qf] *= alpha;
#pragma unroll
            for (int df = 0; df < 8; ++df)
              oacc[qf][df] *= alpha;
          }
        }
        uint w[2][4][2];
#pragma unroll
        for (int qf = 0; qf < 2; ++qf) {
          const float mn = m_[qf];
          float lsum = 0.f;
#pragma unroll
          for (int kvf = 0; kvf < 4; ++kvf) {
            const float p0 = __builtin_exp2f((s[qf][kvf][0] - mn) * SCL2);
            const float p1 = __builtin_exp2f((s[qf][kvf][1] - mn) * SCL2);
            const float p2 = __builtin_exp2f((s[qf][kvf][2] - mn) * SCL2);
            const float p3 = __builtin_exp2f((s[qf][kvf][3] - mn) * SCL2);
            lsum += (p0 + p1) + (p2 + p3);
            w[qf][kvf][0] = pk2h(p0, p1);
            w[qf][kvf][1] = pk2h(p2, p3);
          }
          l_[qf] += lsum;
        }
        const bool ghi = g >= 2;
        const bool godd = (g & 1) != 0;
        half8 pb[2][2];
#pragma unroll
        for (int qf = 0; qf < 2; ++qf) {
          uint sA[2][2], sB[2][2];
#pragma unroll
          for (int c = 0; c < 2; ++c)
#pragma unroll
            for (int i = 0; i < 2; ++i) {
              sA[c][i] = ghi ? w[qf][2 * c + 1][i] : w[qf][2 * c][i];
              sB[c][i] = ghi ? w[qf][2 * c][i] : w[qf][2 * c + 1][i];
            }
          uint x16[2][2], x32[2][2], x48[2][2];
#pragma unroll
          for (int c = 0; c < 2; ++c)
#pragma unroll
            for (int i = 0; i < 2; ++i) {
              x16[c][i] = __shfl_xor(sA[c][i], 16);
              x32[c][i] = __shfl_xor(sB[c][i], 32);
              x48[c][i] = __shfl_xor(sB[c][i], 48);
            }
#pragma unroll
          for (int c = 0; c < 2; ++c) {
            uint4 t;
            t.x = godd ? (ghi ? x16[c][0] : x48[c][0]) : (ghi ? x32[c][0] : sA[c][0]);
            t.y = godd ? (ghi ? x16[c][1] : x48[c][1]) : (ghi ? x32[c][1] : sA[c][1]);
            t.z = godd ? (ghi ? sA[c][0] : x32[c][0]) : (ghi ? x48[c][0] : x16[c][0]);
            t.w = godd ? (ghi ? sA[c][1] : x32[c][1]) : (ghi ? x48[c][1] : x16[c][1]);
            pb[qf][c] = __builtin_bit_cast(half8, t);
          }
        }
        __builtin_amdgcn_s_setprio(1);
#pragma unroll
        for (int c = 0; c < 2; ++c) {
#pragma unroll
          for (int df = 0; df < 8; ++df) {
            const int d = df * 16 + q16;
            const half8 vf = *(const half8*)&Vtb[(d * 64 + c * 32 + g * 8) ^ ((d & 7) << 3)];
#pragma unroll
            for (int qf = 0; qf < 2; ++qf)
              oacc[qf][df] = MFMA(vf, pb[qf][c], oacc[qf][df]);
          }
        }
        __builtin_amdgcn_s_setprio(0);
      }

      if (kt + 1 < nt) WRITEV(cur ^ 1);
    }

#pragma unroll
    for (int qf = 0; qf < 2; ++qf) {
      float l = l_[qf];
      l += __shfl_xor(l, 16);
      l += __shfl_xor(l, 32);
      const float inv = 1.0f / l;
      const int t = qrow + qf * 16 + q16;
#pragma unroll
      for (int df = 0; df < 8; ++df) {
        const f32x4 v = oacc[qf][df];
        ushort4 o;
        o.x = f2h(v[0] * inv); o.y = f2h(v[1] * inv);
        o.z = f2h(v[2] * inv); o.w = f2h(v[3] * inv);
        *(ushort4*)(O + headbase + (size_t)t * Dc + df * 16 + g * 4) = o;
      }
    }
  }
#undef ISSUEK
#undef LOADV
#undef WRITEV
}

extern "C" void kernel_launch(void* const* d_in, const int* in_sizes, int n_in,
                              void* d_out, int out_size, void* d_ws, size_t ws_size,
                              hipStream_t stream) {
  (void)in_sizes; (void)n_in; (void)out_size; (void)ws_size;
  const float* x  = (const float*)d_in[0];
  const float* cs = (const float*)d_in[1];
  const float* sn = (const float*)d_in[2];
  // d_in[3] = mask (unused: causal handled analytically)
  const float* Wq = (const float*)d_in[4];
  const float* Wk = (const float*)d_in[5];
  const float* Wv = (const float*)d_in[6];
  const float* Wo = (const float*)d_in[7];
  float* out = (float*)d_out;

  char* ws = (char*)d_ws;
  const size_t MB = 1024 * 1024;
  ushort* xb  = (ushort*)(ws);            // 32MB x fp16; reused as attn output O
  ushort* wqb = (ushort*)(ws + 32 * MB);  // wq,wk,wv,wo CONTIGUOUS 8MB each
  ushort* wob = (ushort*)(ws + 56 * MB);
  ushort* Qr  = (ushort*)(ws + 64 * MB);  // Qr,Kr,Vr CONTIGUOUS 32MB each
  ushort* Kr  = (ushort*)(ws + 96 * MB);
  ushort* Vr  = (ushort*)(ws + 128 * MB); // end: 160MB

  cvtall<<<32768, 256, 0, stream>>>(x, Wq, Wk, Wv, Wo, xb, wqb);

  gemmqkv<<<768, 512, 0, stream>>>(xb, wqb, Qr, cs, sn);

  attn<<<dim3(4, 64), 512, 0, stream>>>(Qr, Kr, Vr, xb);

  gemm256<float><<<256, 512, 0, stream>>>(xb, wob, out);
}

// Round 23
// 449.044 us; speedup vs baseline: 1.0126x; 1.0126x over previous
//
#include <hip/hip_runtime.h>
#include <hip/hip_bf16.h>

#define DEV static __device__ __forceinline__

typedef __attribute__((ext_vector_type(8))) _Float16 half8;   // A/B frag: 8 fp16 = 4 VGPR
typedef __attribute__((ext_vector_type(4))) float f32x4;      // C/D frag

constexpr int Bc = 4, Tc = 2048, Dc = 2048, Hc = 16;          // HD = 128

DEV ushort f2h(float f) { _Float16 h = (_Float16)f; return __builtin_bit_cast(ushort, h); }
DEV float  h2f(ushort u) { return (float)__builtin_bit_cast(_Float16, u); }
DEV uint pk2h(float a, float b) {
  return __builtin_bit_cast(uint, __builtin_amdgcn_cvt_pkrtz(a, b));
}

DEV f32x4 MFMA(half8 a, half8 b, f32x4 c) {
  return __builtin_amdgcn_mfma_f32_16x16x32_f16(a, b, c, 0, 0, 0);
}

DEV void async_cp16(void* lds, const void* g) {
  __builtin_amdgcn_global_load_lds((const __attribute__((address_space(1))) void*)g,
                                   (__attribute__((address_space(3))) void*)lds,
                                   16, 0, 0);
}

// ---- fused convert: x (blk<16384) + 4 weights (blk>=16384, Wq/Wk RoPE-perm)
// GRID = 32768.
__global__ __launch_bounds__(256) void cvtall(const float* __restrict__ x,
                                              const float* __restrict__ w0,
                                              const float* __restrict__ w1,
                                              const float* __restrict__ w2,
                                              const float* __restrict__ w3,
                                              ushort* __restrict__ xb,
                                              ushort* __restrict__ wb) {
  const int blk = (int)blockIdx.x;
  if (blk < 16384) {                    // x: 4M vec4
    const int i = blk * 256 + (int)threadIdx.x;
    const float4 v = ((const float4*)x)[i];
    ushort4 o;
    o.x = f2h(v.x); o.y = f2h(v.y); o.z = f2h(v.z); o.w = f2h(v.w);
    ((ushort4*)xb)[i] = o;
    return;
  }
  const int wblk = blk - 16384;         // 0..16383 (4096 blocks per weight)
  const int wsel = wblk >> 12;          // 0:Wq 1:Wk 2:Wv 3:Wo
  const int i = (wblk & 4095) * 256 + (int)threadIdx.x;  // vec4 idx, 1M per W
  const float* in = (wsel == 0) ? w0 : (wsel == 1) ? w1 : (wsel == 2) ? w2 : w3;
  const float4 v = ((const float4*)in)[i];
  ushort4 o;
  o.x = f2h(v.x); o.y = f2h(v.y); o.z = f2h(v.z); o.w = f2h(v.w);
  int row = i >> 9;
  const int cidx = i & 511;
  if (wsel < 2) {                       // RoPE row permutation for Wq/Wk
    const int h = row >> 7, fr = row & 127;
    const int s_ = fr >> 6, j = fr & 63;
    row = h * 128 + (j >> 4) * 32 + s_ * 16 + (j & 15);
  }
  ((ushort4*)wb)[((size_t)wsel << 20) + row * 512 + cidx] = o;
}

// ---------------- fused QKV GEMM 256x256, BK=32, 4-slot ring --------------
// ROUND-17 EXACT (measured optimum: 201.5us, MfmaUtil 47.5%). Schedule
// ladder fully measured: 4-phase 72 / 2-phase 64 / THIS 63 / pre-issue 68.6
// / BK=64-drain0 71 (r22: draining vmcnt to 0 per iter exposes staging
// latency — T4's counted wait is the load-bearing element).
__global__ __launch_bounds__(512, 2) void gemmqkv(const ushort* __restrict__ A,
                                                  const ushort* __restrict__ Bw,
                                                  ushort* __restrict__ Cq,
                                                  const float* __restrict__ cs,
                                                  const float* __restrict__ sn) {
  __shared__ ushort As[4][256 * 32];
  __shared__ ushort Bs[4][256 * 32];
  const int tid = threadIdx.x;                 // 0..511
  const int lane = tid & 63, wid = tid >> 6;   // 8 waves
  const int g = lane >> 4, q16 = lane & 15;
  const int wm = wid >> 2, wn = wid & 3;       // 2M x 4N

  const int flat = (int)blockIdx.x;            // 0..767
  const int xcd = flat & 7, idx = flat >> 3;   // idx 0..95
  const int bm = xcd * 4 + (idx & 3);
  const int bn = idx >> 2;                     // 0..23
  const ushort* Ab = A + (size_t)bm * 256 * Dc;
  const ushort* Bb = Bw + (size_t)bn * 256 * Dc;

#define STAGE1(KT, BUF, PH) do {                                               \
    const int pass_ = (PH) & 1;                                                \
    const int c_ = pass_ * 512 + tid;                                          \
    const int row_ = c_ >> 2, gl_ = c_ & 3;                                    \
    const int col_ = (KT) * 32 + ((gl_ ^ ((row_ >> 1) & 3)) << 3);             \
    if ((PH) < 2)                                                              \
      async_cp16(&As[BUF][(pass_ * 512 + wid * 64) * 8],                       \
                 Ab + (size_t)row_ * Dc + col_);                               \
    else                                                                       \
      async_cp16(&Bs[BUF][(pass_ * 512 + wid * 64) * 8],                       \
                 Bb + (size_t)row_ * Dc + col_);                               \
  } while (0)

  f32x4 acc[8][4] = {};

  for (int tt = 0; tt < 3; ++tt) {
    STAGE1(tt, tt, 0); STAGE1(tt, tt, 1);
    STAGE1(tt, tt, 2); STAGE1(tt, tt, 3);
  }

  const int sgz = (g ^ ((q16 >> 1) & 3)) << 3;

#pragma unroll 1
  for (int t = 0; t < 64; ++t) {
    const int sb = (t + 3) & 3;
    const bool st = (t + 3) < 64;
    const ushort* Asb = As[t & 3];
    const ushort* Bsb = Bs[t & 3];

    if (t + 2 < 64)      asm volatile("s_waitcnt vmcnt(8)" ::: "memory");
    else if (t + 1 < 64) asm volatile("s_waitcnt vmcnt(4)" ::: "memory");
    else                 asm volatile("s_waitcnt vmcnt(0)" ::: "memory");
    __builtin_amdgcn_s_barrier();
    __builtin_amdgcn_sched_barrier(0);

    half8 af0[4], af1[4], bf[4];
#pragma unroll
    for (int nf = 0; nf < 4; ++nf) {
      const int r = wn * 64 + nf * 16 + q16;
      bf[nf] = *(const half8*)&Bsb[r * 32 + sgz];
    }
#pragma unroll
    for (int mf = 0; mf < 4; ++mf) {
      const int r = wm * 128 + mf * 16 + q16;
      af0[mf] = *(const half8*)&Asb[r * 32 + sgz];
    }
#pragma unroll
    for (int mf = 0; mf < 4; ++mf) {
      const int r = wm * 128 + 64 + mf * 16 + q16;
      af1[mf] = *(const half8*)&Asb[r * 32 + sgz];
    }
    if (st) { STAGE1(t + 3, sb, 0); STAGE1(t + 3, sb, 1);
              STAGE1(t + 3, sb, 2); STAGE1(t + 3, sb, 3); }

    __builtin_amdgcn_s_setprio(1);
#pragma unroll
    for (int mf = 0; mf < 4; ++mf)
#pragma unroll
      for (int nf = 0; nf < 4; ++nf)
        acc[mf][nf] = MFMA(af0[mf], bf[nf], acc[mf][nf]);
#pragma unroll
    for (int mf = 0; mf < 4; ++mf)
#pragma unroll
      for (int nf = 0; nf < 4; ++nf)
        acc[4 + mf][nf] = MFMA(af1[mf], bf[nf], acc[4 + mf][nf]);
    __builtin_amdgcn_s_setprio(0);
  }
#undef STAGE1

  ushort* C = Cq + (size_t)(bn >> 3) * ((size_t)8192 * Dc);
  const int bn8 = bn & 7;
  const int m00 = bm * 256 + wm * 128 + g * 4;
  const int n0 = bn8 * 256 + wn * 64 + q16;

  if (bn < 16) {
#pragma unroll
    for (int mf = 0; mf < 8; ++mf)
#pragma unroll
      for (int p = 0; p < 2; ++p) {
        const int j = ((wn & 1) * 2 + p) * 16 + q16;
#pragma unroll
        for (int r = 0; r < 4; ++r) {
          const int m = m00 + mf * 16 + r;
          const int t = m & (Tc - 1);
          const float c = cs[t * 128 + j];
          const float s_ = sn[t * 128 + j];
          const float lo = acc[mf][2 * p][r];
          const float hi = acc[mf][2 * p + 1][r];
          C[(size_t)m * Dc + n0 + (2 * p) * 16] = f2h(lo * c - hi * s_);
          C[(size_t)m * Dc + n0 + (2 * p + 1) * 16] = f2h(hi * c + lo * s_);
        }
      }
  } else {
#pragma unroll
    for (int mf = 0; mf < 8; ++mf)
#pragma unroll
      for (int nf = 0; nf < 4; ++nf) {
        const int m0 = m00 + mf * 16;
        const int n = n0 + nf * 16;
#pragma unroll
        for (int r = 0; r < 4; ++r)
          C[(size_t)(m0 + r) * Dc + n] = f2h(acc[mf][nf][r]);
      }
  }
}

// ---------------- GEMM 256x256 (final projection, f32 out) -- r17 exact ----
template <typename OutT>
__global__ __launch_bounds__(512, 2) void gemm256(const ushort* __restrict__ A,
                                                  const ushort* __restrict__ Bw,
                                                  OutT* __restrict__ C) {
  __shared__ ushort As[4][256 * 32];
  __shared__ ushort Bs[4][256 * 32];
  const int tid = threadIdx.x;
  const int lane = tid & 63, wid = tid >> 6;
  const int g = lane >> 4, q16 = lane & 15;
  const int wm = wid >> 2, wn = wid & 3;

  const int flat = (int)blockIdx.x;            // 0..255
  const int xcd = flat & 7, idx = flat >> 3;
  const int bm = xcd * 4 + (idx & 3);
  const int bn = idx >> 2;
  const ushort* Ab = A + (size_t)bm * 256 * Dc;
  const ushort* Bb = Bw + (size_t)bn * 256 * Dc;

#define STAGE1(KT, BUF, PH) do {                                               \
    const int pass_ = (PH) & 1;                                                \
    const int c_ = pass_ * 512 + tid;                                          \
    const int row_ = c_ >> 2, gl_ = c_ & 3;                                    \
    const int col_ = (KT) * 32 + ((gl_ ^ ((row_ >> 1) & 3)) << 3);             \
    if ((PH) < 2)                                                              \
      async_cp16(&As[BUF][(pass_ * 512 + wid * 64) * 8],                       \
                 Ab + (size_t)row_ * Dc + col_);                               \
    else                                                                       \
      async_cp16(&Bs[BUF][(pass_ * 512 + wid * 64) * 8],                       \
                 Bb + (size_t)row_ * Dc + col_);                               \
  } while (0)

  f32x4 acc[8][4] = {};

  for (int tt = 0; tt < 3; ++tt) {
    STAGE1(tt, tt, 0); STAGE1(tt, tt, 1);
    STAGE1(tt, tt, 2); STAGE1(tt, tt, 3);
  }

  const int sgz = (g ^ ((q16 >> 1) & 3)) << 3;

#pragma unroll 1
  for (int t = 0; t < 64; ++t) {
    const int sb = (t + 3) & 3;
    const bool st = (t + 3) < 64;
    const ushort* Asb = As[t & 3];
    const ushort* Bsb = Bs[t & 3];

    if (t + 2 < 64)      asm volatile("s_waitcnt vmcnt(8)" ::: "memory");
    else if (t + 1 < 64) asm volatile("s_waitcnt vmcnt(4)" ::: "memory");
    else                 asm volatile("s_waitcnt vmcnt(0)" ::: "memory");
    __builtin_amdgcn_s_barrier();
    __builtin_amdgcn_sched_barrier(0);

    half8 af0[4], af1[4], bf[4];
#pragma unroll
    for (int nf = 0; nf < 4; ++nf) {
      const int r = wn * 64 + nf * 16 + q16;
      bf[nf] = *(const half8*)&Bsb[r * 32 + sgz];
    }
#pragma unroll
    for (int mf = 0; mf < 4; ++mf) {
      const int r = wm * 128 + mf * 16 + q16;
      af0[mf] = *(const half8*)&Asb[r * 32 + sgz];
    }
#pragma unroll
    for (int mf = 0; mf < 4; ++mf) {
      const int r = wm * 128 + 64 + mf * 16 + q16;
      af1[mf] = *(const half8*)&Asb[r * 32 + sgz];
    }
    if (st) { STAGE1(t + 3, sb, 0); STAGE1(t + 3, sb, 1);
              STAGE1(t + 3, sb, 2); STAGE1(t + 3, sb, 3); }

    __builtin_amdgcn_s_setprio(1);
#pragma unroll
    for (int mf = 0; mf < 4; ++mf)
#pragma unroll
      for (int nf = 0; nf < 4; ++nf)
        acc[mf][nf] = MFMA(af0[mf], bf[nf], acc[mf][nf]);
#pragma unroll
    for (int mf = 0; mf < 4; ++mf)
#pragma unroll
      for (int nf = 0; nf < 4; ++nf)
        acc[4 + mf][nf] = MFMA(af1[mf], bf[nf], acc[4 + mf][nf]);
    __builtin_amdgcn_s_setprio(0);
  }
#undef STAGE1

  const int m00 = bm * 256 + wm * 128 + g * 4;
  const int n0 = bn * 256 + wn * 64 + q16;
#pragma unroll
  for (int mf = 0; mf < 8; ++mf)
#pragma unroll
    for (int nf = 0; nf < 4; ++nf) {
      const int m0 = m00 + mf * 16;
      const int n = n0 + nf * 16;
#pragma unroll
      for (int r = 0; r < 4; ++r) {
        const float v = acc[mf][nf][r];
        if constexpr (sizeof(OutT) == 2)
          C[(size_t)(m0 + r) * Dc + n] = (OutT)f2h(v);
        else
          C[(size_t)(m0 + r) * Dc + n] = (OutT)v;
      }
    }
}

// ---------------- causal flash attention (2 q-chains / wave) ----------------
// EXACT round-12/13 version (best-known 162us). Q/K feature-PERMUTED.
__global__ __launch_bounds__(512, 2) void attn(const ushort* __restrict__ Q,
                                               const ushort* __restrict__ K,
                                               const ushort* __restrict__ V,
                                               ushort* __restrict__ O) {
  __shared__ ushort Ks[2][64 * 128];   // [kv][d], XOR-swizzled (granule ^= kv&7)
  __shared__ ushort Vt[2][128 * 64];   // [d][kv], XOR-swizzled rows

  const int tid = threadIdx.x;         // 0..511
  const int lane = tid & 63, wid = tid >> 6;   // wid 0..7
  const int g = lane >> 4, q16 = lane & 15;

  const int flat = (int)(blockIdx.x + 4 * blockIdx.y);    // 0..255
  const int xcd = flat & 7, idx = flat >> 3;              // idx 0..31
  const int bh = xcd + 8 * (idx & 7);                     // head-slot 0..63
  const int pr = idx >> 3;                                // supertile pair 0..3

  const int b = bh >> 4, h = bh & 15;
  const size_t headbase = ((size_t)b * Tc * Hc + h) * 128;  // t-stride = 2048
  const float SCL2 = 0.12751743f;      // log2(e)/sqrt(128)

  const int vdc = (wid & 3) * 4 + (lane & 3);         // 0..15: d = vdc*8..+7
  const int vkvp = (wid >> 2) * 16 + (lane >> 2);     // 0..31: kv pair

  uint4 vreg[2];

#define ISSUEK(KT, BUF) do {                                                   \
    const ushort* Kb_ = K + headbase + (size_t)(KT) * 64 * Dc;                 \
    _Pragma("unroll") for (int i_ = 0; i_ < 2; ++i_) {                         \
      const int c_ = i_ * 512 + tid;                                           \
      const int kv_ = c_ >> 4, gl_ = c_ & 15;                                  \
      async_cp16(&Ks[BUF][(i_ * 512 + wid * 64) * 8],                          \
                 Kb_ + (size_t)kv_ * Dc + ((gl_ ^ (kv_ & 7)) << 3));           \
    }                                                                          \
  } while (0)

#define LOADV(KT) do {                                                         \
    const ushort* p0_ = V + headbase + (size_t)((KT) * 64 + 2 * vkvp) * Dc +   \
                        vdc * 8;                                               \
    vreg[0] = *(const uint4*)p0_;                                              \
    vreg[1] = *(const uint4*)(p0_ + Dc);                                       \
  } while (0)

#define WRITEV(BUF) do {                                                       \
    const ushort* e0_ = (const ushort*)&vreg[0];                               \
    const ushort* e1_ = (const ushort*)&vreg[1];                               \
    _Pragma("unroll") for (int j_ = 0; j_ < 8; ++j_) {                         \
      const int d_ = vdc * 8 + j_;                                             \
      const unsigned w_ = (unsigned)e0_[j_] | ((unsigned)e1_[j_] << 16);       \
      *(unsigned*)&Vt[BUF][(d_ * 64 + 2 * vkvp) ^ ((d_ & 7) << 3)] = w_;       \
    }                                                                          \
  } while (0)

#pragma unroll 1
  for (int half = 0; half < 2; ++half) {
    const int q0 = (half ? pr : 7 - pr) * 256;
    const int qrow = q0 + wid * 32;          // wave owns rows qrow..qrow+31
    const int nt = q0 / 64 + 4;

    half8 qreg[2][4];
#pragma unroll
    for (int qf = 0; qf < 2; ++qf)
#pragma unroll
      for (int ds = 0; ds < 4; ++ds)
        qreg[qf][ds] = *(const half8*)(Q + headbase +
                       (size_t)(qrow + qf * 16 + q16) * Dc + ds * 32 + g * 8);

    f32x4 oacc[2][8] = {};             // O^T frags: row=d (g*4+r), col=q
    float m_[2] = {-1e30f, -1e30f};
    float l_[2] = {0.f, 0.f};          // per-lane partials

    __builtin_amdgcn_s_barrier();      // prior half done reading all LDS bufs
    __builtin_amdgcn_sched_barrier(0);
    ISSUEK(0, 0);
    LOADV(0);
    WRITEV(0);                         // compiler waits vmcnt for vreg here

#pragma unroll 1
    for (int kt = 0; kt < nt; ++kt) {
      const int cur = kt & 1;
      const int kv0 = kt * 64;
      asm volatile("s_waitcnt vmcnt(0) lgkmcnt(0)" ::: "memory");
      __builtin_amdgcn_s_barrier();
      __builtin_amdgcn_sched_barrier(0);
      if (kt + 1 < nt) {
        ISSUEK(kt + 1, cur ^ 1);
        LOADV(kt + 1);
      }

      if (kv0 <= qrow + 31) {          // wave-uniform
        const ushort* Ksb = Ks[cur];
        const ushort* Vtb = Vt[cur];
        f32x4 s[2][4] = {};
        __builtin_amdgcn_s_setprio(1);
#pragma unroll
        for (int ds = 0; ds < 4; ++ds) {
          half8 kf[4];
#pragma unroll
          for (int kvf = 0; kvf < 4; ++kvf) {
            const int kv = kvf * 16 + q16;
            kf[kvf] = *(const half8*)&Ksb[(kv * 128 + ds * 32 + g * 8) ^ ((kv & 7) << 3)];
          }
#pragma unroll
          for (int kvf = 0; kvf < 4; ++kvf)
#pragma unroll
            for (int qf = 0; qf < 2; ++qf)
              s[qf][kvf] = MFMA(kf[kvf], qreg[qf][ds], s[qf][kvf]);
        }
        __builtin_amdgcn_s_setprio(0);
        float pmax[2] = {-1e30f, -1e30f};
        if (kv0 + 63 > qrow) {
#pragma unroll
          for (int qf = 0; qf < 2; ++qf) {
            const int qg = qrow + qf * 16 + q16;
#pragma unroll
            for (int kvf = 0; kvf < 4; ++kvf)
#pragma unroll
              for (int r = 0; r < 4; ++r) {
                float v = s[qf][kvf][r];
                if ((kv0 + kvf * 16 + g * 4 + r) > qg) v = -1e30f;
                s[qf][kvf][r] = v;
                pmax[qf] = fmaxf(pmax[qf], v);
              }
          }
        } else {
#pragma unroll
          for (int qf = 0; qf < 2; ++qf)
#pragma unroll
            for (int kvf = 0; kvf < 4; ++kvf)
#pragma unroll
              for (int r = 0; r < 4; ++r)
                pmax[qf] = fmaxf(pmax[qf], s[qf][kvf][r]);
        }
#pragma unroll
        for (int qf = 0; qf < 2; ++qf) {
          pmax[qf] = fmaxf(pmax[qf], __shfl_xor(pmax[qf], 16));
          pmax[qf] = fmaxf(pmax[qf], __shfl_xor(pmax[qf], 32));
        }
        if (!__all((pmax[0] <= m_[0] + 16.f) & (pmax[1] <= m_[1] + 16.f))) {
#pragma unroll
          for (int qf = 0; qf < 2; ++qf) {
            const float mn2 = fmaxf(m_[qf], pmax[qf]);
            const float alpha = __builtin_exp2f((m_[qf] - mn2) * SCL2);
            m_[qf] = mn2;
            l_[qf] *= alpha;
#pragma unroll
            for (int df = 0; df < 8; ++df)
              oacc[qf][df] *= alpha;
          }
        }
        uint w[2][4][2];
#pragma unroll
        for (int qf = 0; qf < 2; ++qf) {
          const float mn = m_[qf];
          float lsum = 0.f;
#pragma unroll
          for (int kvf = 0; kvf < 4; ++kvf) {
            const float p0 = __builtin_exp2f((s[qf][kvf][0] - mn) * SCL2);
            const float p1 = __builtin_exp2f((s[qf][kvf][1] - mn) * SCL2);
            const float p2 = __builtin_exp2f((s[qf][kvf][2] - mn) * SCL2);
            const float p3 = __builtin_exp2f((s[qf][kvf][3] - mn) * SCL2);
            lsum += (p0 + p1) + (p2 + p3);
            w[qf][kvf][0] = pk2h(p0, p1);
            w[qf][kvf][1] = pk2h(p2, p3);
          }
          l_[qf] += lsum;
        }
        const bool ghi = g >= 2;
        const bool godd = (g & 1) != 0;
        half8 pb[2][2];
#pragma unroll
        for (int qf = 0; qf < 2; ++qf) {
          uint sA[2][2], sB[2][2];
#pragma unroll
          for (int c = 0; c < 2; ++c)
#pragma unroll
            for (int i = 0; i < 2; ++i) {
              sA[c][i] = ghi ? w[qf][2 * c + 1][i] : w[qf][2 * c][i];
              sB[c][i] = ghi ? w[qf][2 * c][i] : w[qf][2 * c + 1][i];
            }
          uint x16[2][2], x32[2][2], x48[2][2];
#pragma unroll
          for (int c = 0; c < 2; ++c)
#pragma unroll
            for (int i = 0; i < 2; ++i) {
              x16[c][i] = __shfl_xor(sA[c][i], 16);
              x32[c][i] = __shfl_xor(sB[c][i], 32);
              x48[c][i] = __shfl_xor(sB[c][i], 48);
            }
#pragma unroll
          for (int c = 0; c < 2; ++c) {
            uint4 t;
            t.x = godd ? (ghi ? x16[c][0] : x48[c][0]) : (ghi ? x32[c][0] : sA[c][0]);
            t.y = godd ? (ghi ? x16[c][1] : x48[c][1]) : (ghi ? x32[c][1] : sA[c][1]);
            t.z = godd ? (ghi ? sA[c][0] : x32[c][0]) : (ghi ? x48[c][0] : x16[c][0]);
            t.w = godd ? (ghi ? sA[c][1] : x32[c][1]) : (ghi ? x48[c][1] : x16[c][1]);
            pb[qf][c] = __builtin_bit_cast(half8, t);
          }
        }
        __builtin_amdgcn_s_setprio(1);
#pragma unroll
        for (int c = 0; c < 2; ++c) {
#pragma unroll
          for (int df = 0; df < 8; ++df) {
            const int d = df * 16 + q16;
            const half8 vf = *(const half8*)&Vtb[(d * 64 + c * 32 + g * 8) ^ ((d & 7) << 3)];
#pragma unroll
            for (int qf = 0; qf < 2; ++qf)
              oacc[qf][df] = MFMA(vf, pb[qf][c], oacc[qf][df]);
          }
        }
        __builtin_amdgcn_s_setprio(0);
      }

      if (kt + 1 < nt) WRITEV(cur ^ 1);
    }

#pragma unroll
    for (int qf = 0; qf < 2; ++qf) {
      float l = l_[qf];
      l += __shfl_xor(l, 16);
      l += __shfl_xor(l, 32);
      const float inv = 1.0f / l;
      const int t = qrow + qf * 16 + q16;
#pragma unroll
      for (int df = 0; df < 8; ++df) {
        const f32x4 v = oacc[qf][df];
        ushort4 o;
        o.x = f2h(v[0] * inv); o.y = f2h(v[1] * inv);
        o.z = f2h(v[2] * inv); o.w = f2h(v[3] * inv);
        *(ushort4*)(O + headbase + (size_t)t * Dc + df * 16 + g * 4) = o;
      }
    }
  }
#undef ISSUEK
#undef LOADV
#undef WRITEV
}

extern "C" void kernel_launch(void* const* d_in, const int* in_sizes, int n_in,
                              void* d_out, int out_size, void* d_ws, size_t ws_size,
                              hipStream_t stream) {
  (void)in_sizes; (void)n_in; (void)out_size; (void)ws_size;
  const float* x  = (const float*)d_in[0];
  const float* cs = (const float*)d_in[1];
  const float* sn = (const float*)d_in[2];
  // d_in[3] = mask (unused: causal handled analytically)
  const float* Wq = (const float*)d_in[4];
  const float* Wk = (const float*)d_in[5];
  const float* Wv = (const float*)d_in[6];
  const float* Wo = (const float*)d_in[7];
  float* out = (float*)d_out;

  char* ws = (char*)d_ws;
  const size_t MB = 1024 * 1024;
  ushort* xb  = (ushort*)(ws);            // 32MB x fp16; reused as attn output O
  ushort* wqb = (ushort*)(ws + 32 * MB);  // wq,wk,wv,wo CONTIGUOUS 8MB each
  ushort* wob = (ushort*)(ws + 56 * MB);
  ushort* Qr  = (ushort*)(ws + 64 * MB);  // Qr,Kr,Vr CONTIGUOUS 32MB each
  ushort* Kr  = (ushort*)(ws + 96 * MB);
  ushort* Vr  = (ushort*)(ws + 128 * MB); // end: 160MB

  cvtall<<<32768, 256, 0, stream>>>(x, Wq, Wk, Wv, Wo, xb, wqb);

  gemmqkv<<<768, 512, 0, stream>>>(xb, wqb, Qr, cs, sn);

  attn<<<dim3(4, 64), 512, 0, stream>>>(Qr, Kr, Vr, xb);

  gemm256<float><<<256, 512, 0, stream>>>(xb, wob, out);
}